// Round 1
// baseline (338.846 us; speedup 1.0000x reference)
//
#include <hip/hip_runtime.h>

// Problem constants (fixed by setup_inputs)
#define B 4
#define N 2048      // N1 == N2
#define F 256
#define O 256
#define LRELU_ALPHA 0.2f
#define NEG_BIG -9000000000000000.0f

// Workspace layout (floats):
//  [0,256)       v1 = W1 @ w3a
//  [256,512)     v2 = W2 @ w3b
//  [512, +8192)  t1[b*N+n2] = word . v1   (== s1)
//  [8704,+8192)  t2[b*N+n2] = word . v2
//  [16896,+8192) s2[b*N+n1]
//  [25088,+8192) m[b*N+n1]   (row max of logits)
//  [33280,+8192) zinv[b*N+n1] (1 / softmax denominator)
#define WS_V1   0
#define WS_V2   256
#define WS_T1   512
#define WS_T2   (512 + B*N)
#define WS_S2   (512 + 2*B*N)
#define WS_M    (512 + 3*B*N)
#define WS_ZI   (512 + 4*B*N)

// ---------------- kernel 1: v1 = W1 @ w3a, v2 = W2 @ w3b ----------------
// grid 64 blocks x 256 threads; one wave per output row f.
__global__ __launch_bounds__(256) void k_v(const float* __restrict__ W1,
                                           const float* __restrict__ W2,
                                           const float* __restrict__ w3,
                                           float* __restrict__ ws) {
  int tid = threadIdx.x;
  int lane = tid & 63;
  int f = blockIdx.x * 4 + (tid >> 6);
  float a = 0.f, b = 0.f;
  #pragma unroll
  for (int k = 0; k < 4; ++k) {
    int o = lane + 64 * k;
    a += W1[f * O + o] * w3[o];
    b += W2[f * O + o] * w3[O + o];
  }
  #pragma unroll
  for (int off = 32; off > 0; off >>= 1) {
    a += __shfl_down(a, off);
    b += __shfl_down(b, off);
  }
  if (lane == 0) {
    ws[WS_V1 + f] = a;
    ws[WS_V2 + f] = b;
  }
}

// ---------------- kernel 2: t1/t2 row dots ----------------
// grid B*N blocks x 256 threads; one block per (b, n2) row of word.
__global__ __launch_bounds__(256) void k_t(const float* __restrict__ word,
                                           float* __restrict__ ws) {
  const float* v1 = ws + WS_V1;
  const float* v2 = ws + WS_V2;
  float* t1 = ws + WS_T1;
  float* t2 = ws + WS_T2;
  int row = blockIdx.x;
  int f = threadIdx.x;
  float w = word[(size_t)row * F + f];
  float a = w * v1[f];
  float b = w * v2[f];
  #pragma unroll
  for (int off = 32; off > 0; off >>= 1) {
    a += __shfl_down(a, off);
    b += __shfl_down(b, off);
  }
  __shared__ float sa[4], sb[4];
  int wid = f >> 6;
  if ((f & 63) == 0) { sa[wid] = a; sb[wid] = b; }
  __syncthreads();
  if (f == 0) {
    t1[row] = sa[0] + sa[1] + sa[2] + sa[3];
    t2[row] = sb[0] + sb[1] + sb[2] + sb[3];
  }
}

// ---------------- kernel 3: per-row stats (deg, s2, max, 1/Z) ----------------
// grid B*N blocks x 256 threads; one block per (b, n1) row of adj.
__global__ __launch_bounds__(256) void k_stats(const float* __restrict__ adj,
                                               float* __restrict__ ws) {
  const float* t1 = ws + WS_T1;
  const float* t2 = ws + WS_T2;
  float* s2o = ws + WS_S2;
  float* mo  = ws + WS_M;
  float* zio = ws + WS_ZI;

  int row = blockIdx.x;          // b*N + n1
  int b = row >> 11;             // N == 2048
  const float* arow = adj + (size_t)row * N;
  const float* t1b = t1 + b * N;
  const float* t2b = t2 + b * N;
  int tid = threadIdx.x;
  int wid = tid >> 6, lane = tid & 63;

  // pass 1: deg and adj . t2
  float av[8];
  float deg = 0.f, dot = 0.f;
  #pragma unroll
  for (int k = 0; k < 8; ++k) {
    int j = tid + k * 256;
    float a = arow[j];
    av[k] = a;
    deg += a;
    dot += a * t2b[j];
  }
  #pragma unroll
  for (int off = 32; off > 0; off >>= 1) {
    deg += __shfl_down(deg, off);
    dot += __shfl_down(dot, off);
  }
  __shared__ float rd[4], rt[4], rm[4], rz[4];
  if (lane == 0) { rd[wid] = deg; rt[wid] = dot; }
  __syncthreads();
  deg = rd[0] + rd[1] + rd[2] + rd[3];
  dot = rt[0] + rt[1] + rt[2] + rt[3];
  float degc = deg > 0.f ? deg : 1.f;
  float s2 = dot / degc;

  // pass 2: logits (alpha or NEG_BIG) + row max
  float al[8];
  float m = -3.4e38f;
  #pragma unroll
  for (int k = 0; k < 8; ++k) {
    int j = tid + k * 256;
    float v;
    if (av[k] > 0.f) {
      float pre = t1b[j] + s2;
      float lr = pre >= 0.f ? pre : LRELU_ALPHA * pre;
      v = expf(lr);          // alpha
    } else {
      v = NEG_BIG;
    }
    al[k] = v;
    m = fmaxf(m, v);
  }
  #pragma unroll
  for (int off = 32; off > 0; off >>= 1) m = fmaxf(m, __shfl_down(m, off));
  if (lane == 0) rm[wid] = m;
  __syncthreads();
  m = fmaxf(fmaxf(rm[0], rm[1]), fmaxf(rm[2], rm[3]));

  // pass 3: Z = sum exp(al - m)
  float z = 0.f;
  #pragma unroll
  for (int k = 0; k < 8; ++k) z += expf(al[k] - m);
  #pragma unroll
  for (int off = 32; off > 0; off >>= 1) z += __shfl_down(z, off);
  if (lane == 0) rz[wid] = z;
  __syncthreads();
  if (tid == 0) {
    z = rz[0] + rz[1] + rz[2] + rz[3];
    s2o[row] = s2;
    mo[row] = m;
    zio[row] = 1.0f / z;
  }
}

// ---------------- kernel 4: edge = softmax_weights @ word ----------------
// grid (B*N/TM) blocks x 256 threads. Each block: TM=16 rows x 256 cols.
// Thread layout: fgrp = tid&63 (4 f-cols via float4), rgrp = tid>>6 (4 rows).
#define TM 16
#define TJ 128
#define WTP 20   // padded row stride for wt (16B-aligned float4 reads, fewer write conflicts)

__global__ __launch_bounds__(256) void k_main(const float* __restrict__ adj,
                                              const float* __restrict__ word,
                                              const float* __restrict__ ws,
                                              float* __restrict__ out) {
  const float* t1  = ws + WS_T1;
  const float* s2a = ws + WS_S2;
  const float* ma  = ws + WS_M;
  const float* zia = ws + WS_ZI;

  int brow0 = blockIdx.x * TM;       // global row in [0, B*N)
  int b = brow0 >> 11;
  const float* t1b = t1 + b * N;
  const float* wb  = word + (size_t)b * N * F;

  __shared__ float wt[TJ][WTP];      // [j][r] weights, padded
  __shared__ float ss2[TM], sm[TM], szi[TM];

  int tid = threadIdx.x;
  if (tid < TM) {
    ss2[tid] = s2a[brow0 + tid];
    sm[tid]  = ma[brow0 + tid];
    szi[tid] = zia[brow0 + tid];
  }
  __syncthreads();

  int fgrp = tid & 63;
  int rgrp = tid >> 6;
  int f0 = fgrp * 4;
  int rbase = rgrp * 4;

  float4 acc0 = {0,0,0,0}, acc1 = {0,0,0,0}, acc2 = {0,0,0,0}, acc3 = {0,0,0,0};

  for (int j0 = 0; j0 < N; j0 += TJ) {
    // cooperative weight tile: TM*TJ = 2048 entries, 8 per thread
    #pragma unroll
    for (int k = 0; k < (TM * TJ) / 256; ++k) {
      int idx = tid + k * 256;
      int r = idx >> 7;             // idx / TJ
      int j = idx & (TJ - 1);
      float a = adj[(size_t)(brow0 + r) * N + j0 + j];
      float mr = sm[r];
      float al;
      if (a > 0.f) {
        float pre = t1b[j0 + j] + ss2[r];
        float lr = pre >= 0.f ? pre : LRELU_ALPHA * pre;
        al = expf(lr);
      } else {
        al = NEG_BIG;
      }
      wt[j][r] = expf(al - mr) * szi[r];
    }
    __syncthreads();

    #pragma unroll 4
    for (int j = 0; j < TJ; ++j) {
      const float4 wv = *(const float4*)(wb + (size_t)(j0 + j) * F + f0);
      const float4 ww = *(const float4*)(&wt[j][rbase]);
      acc0.x += ww.x * wv.x; acc0.y += ww.x * wv.y; acc0.z += ww.x * wv.z; acc0.w += ww.x * wv.w;
      acc1.x += ww.y * wv.x; acc1.y += ww.y * wv.y; acc1.z += ww.y * wv.z; acc1.w += ww.y * wv.w;
      acc2.x += ww.z * wv.x; acc2.y += ww.z * wv.y; acc2.z += ww.z * wv.z; acc2.w += ww.z * wv.w;
      acc3.x += ww.w * wv.x; acc3.y += ww.w * wv.y; acc3.z += ww.w * wv.z; acc3.w += ww.w * wv.w;
    }
    __syncthreads();
  }

  float4* o0 = (float4*)(out + (size_t)(brow0 + rbase + 0) * F + f0);
  float4* o1 = (float4*)(out + (size_t)(brow0 + rbase + 1) * F + f0);
  float4* o2 = (float4*)(out + (size_t)(brow0 + rbase + 2) * F + f0);
  float4* o3 = (float4*)(out + (size_t)(brow0 + rbase + 3) * F + f0);
  *o0 = acc0; *o1 = acc1; *o2 = acc2; *o3 = acc3;
}

extern "C" void kernel_launch(void* const* d_in, const int* in_sizes, int n_in,
                              void* d_out, int out_size, void* d_ws, size_t ws_size,
                              hipStream_t stream) {
  const float* word = (const float*)d_in[0];
  const float* adj  = (const float*)d_in[1];
  const float* W1   = (const float*)d_in[2];
  const float* W2   = (const float*)d_in[3];
  const float* w3   = (const float*)d_in[4];
  float* out = (float*)d_out;
  float* ws  = (float*)d_ws;

  k_v<<<64, 256, 0, stream>>>(W1, W2, w3, ws);
  k_t<<<B * N, 256, 0, stream>>>(word, ws);
  k_stats<<<B * N, 256, 0, stream>>>(adj, ws);
  k_main<<<(B * N) / TM, 256, 0, stream>>>(adj, word, ws, out);
}

// Round 2
// 154.361 us; speedup vs baseline: 2.1952x; 2.1952x over previous
//
#include <hip/hip_runtime.h>

#define B 4
#define N 2048      // N1 == N2
#define F 256
#define O 256
#define LOG2E 1.4426950408889634f
#define NEG_BIG -9000000000000000.0f

typedef _Float16 f16;
typedef f16 f16x8 __attribute__((ext_vector_type(8)));
typedef f16 f16x4 __attribute__((ext_vector_type(4)));
typedef float f32x4 __attribute__((ext_vector_type(4)));

// ws float-index layout
#define WS_V1 0
#define WS_V2 256
#define WS_T1 512              // t1 * LOG2E  per (b,n2)
#define WS_T2 (512 + B*N)     // t2 (unscaled) per (b,n2)
#define WS_S2 (512 + 2*B*N)   // s2 * LOG2E  per (b,n1)
#define WS_CR (512 + 3*B*N)   // -m*LOG2E - log2(Z)
#define WS_WN (512 + 4*B*N)   // weight for adj==0 entries (0, or 1/N for deg==0)
// byte offsets in d_ws
#define WT_OFF (1u << 20)     // wordT: f16 [B][F][N]  (4 MB)
#define MK_OFF (6u << 20)     // mask:  u8 [B*N][N/8]  (2 MB)

__device__ __forceinline__ float alpha_of(float pre2) {
  // alpha = exp(lrelu(pre)); pre2 = pre*LOG2E; lrelu via max(x, 0.2x)
  return __builtin_amdgcn_exp2f(fmaxf(pre2, 0.2f * pre2));
}

// ---------------- kernel 1: v1 = W1 @ w3a, v2 = W2 @ w3b ----------------
__global__ __launch_bounds__(256) void k_v(const float* __restrict__ W1,
                                           const float* __restrict__ W2,
                                           const float* __restrict__ w3,
                                           float* __restrict__ ws) {
  int tid = threadIdx.x;
  int lane = tid & 63;
  int f = blockIdx.x * 4 + (tid >> 6);
  float a = 0.f, b = 0.f;
  #pragma unroll
  for (int k = 0; k < 4; ++k) {
    int o = lane + 64 * k;
    a += W1[f * O + o] * w3[o];
    b += W2[f * O + o] * w3[O + o];
  }
  #pragma unroll
  for (int off = 32; off > 0; off >>= 1) {
    a += __shfl_down(a, off);
    b += __shfl_down(b, off);
  }
  if (lane == 0) {
    ws[WS_V1 + f] = a;
    ws[WS_V2 + f] = b;
  }
}

// ---------------- kernel 2: t1s = (word.v1)*LOG2E, t2 = word.v2 ----------------
__global__ __launch_bounds__(256) void k_t(const float* __restrict__ word,
                                           float* __restrict__ ws) {
  const float* v1 = ws + WS_V1;
  const float* v2 = ws + WS_V2;
  int row = blockIdx.x;
  int f = threadIdx.x;
  float w = word[(size_t)row * F + f];
  float a = w * v1[f];
  float b = w * v2[f];
  #pragma unroll
  for (int off = 32; off > 0; off >>= 1) {
    a += __shfl_down(a, off);
    b += __shfl_down(b, off);
  }
  __shared__ float sa[4], sb[4];
  int wid = f >> 6;
  if ((f & 63) == 0) { sa[wid] = a; sb[wid] = b; }
  __syncthreads();
  if (f == 0) {
    ws[WS_T1 + row] = (sa[0] + sa[1] + sa[2] + sa[3]) * LOG2E;
    ws[WS_T2 + row] = sb[0] + sb[1] + sb[2] + sb[3];
  }
}

// ---------------- kernel 3: wordT[b][f][k] = (f16)word[b][k][f] ----------------
// grid (N/64, F/64, B), 256 threads. 64x64 tile via LDS.
__global__ __launch_bounds__(256) void k_tr(const float* __restrict__ word,
                                            f16* __restrict__ wordT) {
  __shared__ float tile[64][65];
  int t = threadIdx.x;
  int k0 = blockIdx.x * 64, f0 = blockIdx.y * 64, b = blockIdx.z;
  #pragma unroll
  for (int it = 0; it < 4; ++it) {
    int r = (t >> 4) + it * 16;
    int c = (t & 15) * 4;
    float4 v = *(const float4*)(word + ((size_t)b * N + k0 + r) * F + f0 + c);
    tile[r][c] = v.x; tile[r][c + 1] = v.y; tile[r][c + 2] = v.z; tile[r][c + 3] = v.w;
  }
  __syncthreads();
  #pragma unroll
  for (int it = 0; it < 2; ++it) {
    int fr = (t >> 3) + it * 32;
    int kc = (t & 7) * 8;
    f16x8 h;
    #pragma unroll
    for (int j = 0; j < 8; ++j) h[j] = (f16)tile[kc + j][fr];
    *(f16x8*)(wordT + ((size_t)(b * F + f0 + fr)) * N + k0 + kc) = h;
  }
}

// ---------------- kernel 4: per-row stats + packed bitmask ----------------
__global__ __launch_bounds__(256) void k_stats(const float* __restrict__ adj,
                                               float* __restrict__ ws,
                                               unsigned char* __restrict__ mask) {
  int row = blockIdx.x;
  int b = row >> 11;
  int t = threadIdx.x;
  int wid = t >> 6, lane = t & 63;
  const float* arow = adj + (size_t)row * N;
  const float* t1b = ws + WS_T1 + b * N;
  const float* t2b = ws + WS_T2 + b * N;

  float4 a0 = *(const float4*)(arow + t * 8);
  float4 a1 = *(const float4*)(arow + t * 8 + 4);
  float4 u0 = *(const float4*)(t2b + t * 8);
  float4 u1 = *(const float4*)(t2b + t * 8 + 4);
  float deg = a0.x + a0.y + a0.z + a0.w + a1.x + a1.y + a1.z + a1.w;
  float dot = a0.x * u0.x + a0.y * u0.y + a0.z * u0.z + a0.w * u0.w +
              a1.x * u1.x + a1.y * u1.y + a1.z * u1.z + a1.w * u1.w;
  unsigned mb = (a0.x > 0.f ? 1u : 0u) | (a0.y > 0.f ? 2u : 0u) |
                (a0.z > 0.f ? 4u : 0u) | (a0.w > 0.f ? 8u : 0u) |
                (a1.x > 0.f ? 16u : 0u) | (a1.y > 0.f ? 32u : 0u) |
                (a1.z > 0.f ? 64u : 0u) | (a1.w > 0.f ? 128u : 0u);
  mask[(size_t)row * 256 + t] = (unsigned char)mb;

  #pragma unroll
  for (int off = 32; off > 0; off >>= 1) {
    deg += __shfl_down(deg, off);
    dot += __shfl_down(dot, off);
  }
  __shared__ float rd[4], rt[4], rm[4], rz[4];
  if (lane == 0) { rd[wid] = deg; rt[wid] = dot; }
  __syncthreads();
  deg = rd[0] + rd[1] + rd[2] + rd[3];
  dot = rt[0] + rt[1] + rt[2] + rt[3];
  float degc = deg > 0.f ? deg : 1.f;
  float s2p = (dot / degc) * LOG2E;

  float4 p0 = *(const float4*)(t1b + t * 8);
  float4 p1 = *(const float4*)(t1b + t * 8 + 4);
  float al[8];
  al[0] = (mb & 1)   ? alpha_of(p0.x + s2p) : NEG_BIG;
  al[1] = (mb & 2)   ? alpha_of(p0.y + s2p) : NEG_BIG;
  al[2] = (mb & 4)   ? alpha_of(p0.z + s2p) : NEG_BIG;
  al[3] = (mb & 8)   ? alpha_of(p0.w + s2p) : NEG_BIG;
  al[4] = (mb & 16)  ? alpha_of(p1.x + s2p) : NEG_BIG;
  al[5] = (mb & 32)  ? alpha_of(p1.y + s2p) : NEG_BIG;
  al[6] = (mb & 64)  ? alpha_of(p1.z + s2p) : NEG_BIG;
  al[7] = (mb & 128) ? alpha_of(p1.w + s2p) : NEG_BIG;
  float m = NEG_BIG;
  #pragma unroll
  for (int j = 0; j < 8; ++j) m = fmaxf(m, al[j]);
  #pragma unroll
  for (int off = 32; off > 0; off >>= 1) m = fmaxf(m, __shfl_down(m, off));
  if (lane == 0) rm[wid] = m;
  __syncthreads();
  m = fmaxf(fmaxf(rm[0], rm[1]), fmaxf(rm[2], rm[3]));

  float negmL = -m * LOG2E;
  float z = 0.f;
  #pragma unroll
  for (int j = 0; j < 8; ++j) z += __builtin_amdgcn_exp2f(fmaf(al[j], LOG2E, negmL));
  #pragma unroll
  for (int off = 32; off > 0; off >>= 1) z += __shfl_down(z, off);
  if (lane == 0) rz[wid] = z;
  __syncthreads();
  if (t == 0) {
    z = rz[0] + rz[1] + rz[2] + rz[3];
    ws[WS_S2 + row] = s2p;
    if (deg > 0.f) {
      ws[WS_CR + row] = negmL - log2f(z);
      ws[WS_WN + row] = 0.f;
    } else {
      ws[WS_CR + row] = 0.f;
      ws[WS_WN + row] = 1.0f / (float)N;   // uniform softmax over all-NEG_INF row
    }
  }
}

// ---------------- kernel 5: fused weights + fp16 MFMA GEMM ----------------
// grid 512: blockIdx = rb*2 + fh. Block = 32 rows x 128 f. 4 waves:
// wid = h (rowhalf, bit0) | q2<<1 (f-half). Wave = 16 rows x 64 f = 4 MFMA tiles.
#define TR 32
#define TF 128
#define BK 32
#define AP 40   // padded k-stride (halfs) for LDS tiles

__global__ __launch_bounds__(256) void k_gemm(const f16* __restrict__ wordT,
                                              const unsigned char* __restrict__ maskg,
                                              const float* __restrict__ ws,
                                              float* __restrict__ out) {
  __shared__ __align__(16) f16 Bs[TF][AP];
  __shared__ __align__(16) f16 Aw[TR][AP];
  __shared__ __align__(16) float t1S[N];
  __shared__ __align__(16) unsigned maskS[TR][64];
  __shared__ float sS2[TR], sCR[TR], sWN[TR];

  int t = threadIdx.x;
  int rb = blockIdx.x >> 1, fh = blockIdx.x & 1;
  int row0 = rb * TR, fblk = fh * TF;
  int b = row0 >> 11;

  // stage t1 (8 KB) + mask rows (8 KB) + per-row scalars
  {
    const float* t1g = ws + WS_T1 + b * N;
    *(float4*)(t1S + t * 8)     = *(const float4*)(t1g + t * 8);
    *(float4*)(t1S + t * 8 + 4) = *(const float4*)(t1g + t * 8 + 4);
    const uint4* mg = (const uint4*)(maskg + (size_t)(row0 + (t >> 3)) * 256 + (t & 7) * 32);
    uint4* md = (uint4*)&maskS[t >> 3][(t & 7) * 8];
    md[0] = mg[0]; md[1] = mg[1];
    if (t < TR) {
      sS2[t] = ws[WS_S2 + row0 + t];
      sCR[t] = ws[WS_CR + row0 + t];
      sWN[t] = ws[WS_WN + row0 + t];
    }
  }
  __syncthreads();

  int wr = t >> 3, wg = t & 7;          // weight-compute assignment: row, k-group
  float rs2 = sS2[wr], rcr = sCR[wr], rwn = sWN[wr];

  int wid = t >> 6, l = t & 63;
  int h = wid & 1, q2 = wid >> 1;
  int q = l >> 4, li = l & 15;

  f32x4 acc[4] = {{0,0,0,0},{0,0,0,0},{0,0,0,0},{0,0,0,0}};

  const f16* bsrc = wordT + ((size_t)(b * F + fblk + (t >> 1))) * N + (t & 1) * 16;

  for (int k0 = 0; k0 < N; k0 += BK) {
    // phase 1: stage B tile + compute A (weight) tile
    {
      const uint4* src = (const uint4*)(bsrc + k0);
      uint4 v0 = src[0], v1 = src[1];
      uint4* dst = (uint4*)&Bs[t >> 1][(t & 1) * 16];
      dst[0] = v0; dst[1] = v1;
    }
    {
      unsigned mw = maskS[wr][k0 >> 5];
      float4 tv = *(const float4*)(t1S + k0 + wg * 4);
      float wv[4];
      const float tvv[4] = {tv.x, tv.y, tv.z, tv.w};
      #pragma unroll
      for (int j = 0; j < 4; ++j) {
        float al = alpha_of(tvv[j] + rs2);
        float wsel = __builtin_amdgcn_exp2f(fmaf(al, LOG2E, rcr));
        wv[j] = ((mw >> (wg * 4 + j)) & 1) ? wsel : rwn;
      }
      f16x4 hw;
      #pragma unroll
      for (int j = 0; j < 4; ++j) hw[j] = (f16)wv[j];
      *(f16x4*)(&Aw[wr][wg * 4]) = hw;
    }
    __syncthreads();

    // phase 2: MFMA
    const f16x8 af = *(const f16x8*)(&Aw[h * 16 + li][q * 8]);
    #pragma unroll
    for (int ft = 0; ft < 4; ++ft) {
      const f16x8 bf = *(const f16x8*)(&Bs[q2 * 64 + ft * 16 + li][q * 8]);
      acc[ft] = __builtin_amdgcn_mfma_f32_16x16x32_f16(af, bf, acc[ft], 0, 0, 0);
    }
    __syncthreads();
  }

  // epilogue: C row = q*4+i, col = li  (m89-verified layout)
  #pragma unroll
  for (int ft = 0; ft < 4; ++ft) {
    int gf = fblk + q2 * 64 + ft * 16 + li;
    #pragma unroll
    for (int i = 0; i < 4; ++i) {
      int gr = row0 + h * 16 + q * 4 + i;
      out[(size_t)gr * F + gf] = acc[ft][i];
    }
  }
}

extern "C" void kernel_launch(void* const* d_in, const int* in_sizes, int n_in,
                              void* d_out, int out_size, void* d_ws, size_t ws_size,
                              hipStream_t stream) {
  const float* word = (const float*)d_in[0];
  const float* adj  = (const float*)d_in[1];
  const float* W1   = (const float*)d_in[2];
  const float* W2   = (const float*)d_in[3];
  const float* w3   = (const float*)d_in[4];
  float* out = (float*)d_out;
  float* ws  = (float*)d_ws;
  f16* wordT = (f16*)((char*)d_ws + WT_OFF);
  unsigned char* mask = (unsigned char*)d_ws + MK_OFF;

  k_v<<<64, 256, 0, stream>>>(W1, W2, w3, ws);
  k_t<<<B * N, 256, 0, stream>>>(word, ws);
  k_tr<<<dim3(N / 64, F / 64, B), 256, 0, stream>>>(word, wordT);
  k_stats<<<B * N, 256, 0, stream>>>(adj, ws, mask);
  k_gemm<<<(B * N / TR) * (F / TF), 256, 0, stream>>>(wordT, mask, ws, out);
}

// Round 3
// 148.507 us; speedup vs baseline: 2.2817x; 1.0394x over previous
//
#include <hip/hip_runtime.h>

#define B 4
#define N 2048      // N1 == N2
#define F 256
#define O 256
#define LOG2E 1.4426950408889634f
#define NEG_BIG -9000000000000000.0f

typedef _Float16 f16;
typedef f16 f16x8 __attribute__((ext_vector_type(8)));
typedef f16 f16x4 __attribute__((ext_vector_type(4)));
typedef float f32x16 __attribute__((ext_vector_type(16)));

// ws float-index layout
#define WS_V1 0
#define WS_V2 256
#define WS_T1 512              // t1 * LOG2E  per (b,n2)
#define WS_T2 (512 + B*N)     // t2 (unscaled) per (b,n2)
#define WS_S2 (512 + 2*B*N)   // s2 * LOG2E  per (b,n1)
#define WS_CR (512 + 3*B*N)   // -m*LOG2E - log2(Z)
#define WS_WN (512 + 4*B*N)   // weight for adj==0 entries (0, or 1/N for deg==0)
// byte offsets in d_ws
#define WT_OFF (1u << 20)     // wordT: f16 [B][F][N]  (4 MB)
#define MK_OFF (6u << 20)     // mask:  u8 [B*N][N/8]  (2 MB)

__device__ __forceinline__ float alpha_of(float pre2) {
  // alpha = exp(lrelu(pre)); pre2 = pre*LOG2E; lrelu via max(x, 0.2x)
  return __builtin_amdgcn_exp2f(fmaxf(pre2, 0.2f * pre2));
}

// ---------------- kernel 1: v1 = W1 @ w3a, v2 = W2 @ w3b ----------------
__global__ __launch_bounds__(256) void k_v(const float* __restrict__ W1,
                                           const float* __restrict__ W2,
                                           const float* __restrict__ w3,
                                           float* __restrict__ ws) {
  int tid = threadIdx.x;
  int lane = tid & 63;
  int f = blockIdx.x * 4 + (tid >> 6);
  float a = 0.f, b = 0.f;
  #pragma unroll
  for (int k = 0; k < 4; ++k) {
    int o = lane + 64 * k;
    a += W1[f * O + o] * w3[o];
    b += W2[f * O + o] * w3[O + o];
  }
  #pragma unroll
  for (int off = 32; off > 0; off >>= 1) {
    a += __shfl_down(a, off);
    b += __shfl_down(b, off);
  }
  if (lane == 0) {
    ws[WS_V1 + f] = a;
    ws[WS_V2 + f] = b;
  }
}

// ---------------- kernel 2: k_prep = t1/t2 dots + f16 transpose ----------------
// grid (N/32, B), 256 threads. Block: 32 word-rows -> t1,t2 + wordT[f][k] tile.
__global__ __launch_bounds__(256) void k_prep(const float* __restrict__ word,
                                              float* __restrict__ ws,
                                              f16* __restrict__ wordT) {
  __shared__ float v1s[F], v2s[F];
  __shared__ __align__(16) f16 tile[F][40];   // [f][r], 80B row stride (16B aligned)
  int t = threadIdx.x;
  int k0 = blockIdx.x * 32;
  int b = blockIdx.y;

  if (t < 64)       ((float4*)v1s)[t]      = ((const float4*)(ws + WS_V1))[t];
  else if (t < 128) ((float4*)v2s)[t - 64] = ((const float4*)(ws + WS_V2))[t - 64];
  __syncthreads();

  int r = t >> 3;        // 0..31
  int cg = t & 7;
  const float* wrow = word + ((size_t)(b * N + k0 + r)) * F;
  float a = 0.f, bb = 0.f;
  #pragma unroll
  for (int i = 0; i < 8; ++i) {
    int c = i * 32 + cg * 4;
    float4 w = *(const float4*)(wrow + c);
    float4 x1 = *(const float4*)(v1s + c);
    float4 x2 = *(const float4*)(v2s + c);
    a  += w.x * x1.x + w.y * x1.y + w.z * x1.z + w.w * x1.w;
    bb += w.x * x2.x + w.y * x2.y + w.z * x2.z + w.w * x2.w;
    tile[c + 0][r] = (f16)w.x;
    tile[c + 1][r] = (f16)w.y;
    tile[c + 2][r] = (f16)w.z;
    tile[c + 3][r] = (f16)w.w;
  }
  #pragma unroll
  for (int off = 4; off > 0; off >>= 1) {
    a  += __shfl_down(a, off);
    bb += __shfl_down(bb, off);
  }
  if (cg == 0) {
    ws[WS_T1 + b * N + k0 + r] = a * LOG2E;
    ws[WS_T2 + b * N + k0 + r] = bb;
  }
  __syncthreads();

  // thread t writes f-row t: 32 halfs
  f16* dst = wordT + ((size_t)(b * F + t)) * N + k0;
  *(f16x8*)(dst + 0)  = *(const f16x8*)&tile[t][0];
  *(f16x8*)(dst + 8)  = *(const f16x8*)&tile[t][8];
  *(f16x8*)(dst + 16) = *(const f16x8*)&tile[t][16];
  *(f16x8*)(dst + 24) = *(const f16x8*)&tile[t][24];
}

// ---------------- kernel 3: per-row stats + packed bitmask ----------------
__global__ __launch_bounds__(256) void k_stats(const float* __restrict__ adj,
                                               float* __restrict__ ws,
                                               unsigned char* __restrict__ mask) {
  int row = blockIdx.x;
  int b = row >> 11;
  int t = threadIdx.x;
  int wid = t >> 6, lane = t & 63;
  const float* arow = adj + (size_t)row * N;
  const float* t1b = ws + WS_T1 + b * N;
  const float* t2b = ws + WS_T2 + b * N;

  float4 a0 = *(const float4*)(arow + t * 8);
  float4 a1 = *(const float4*)(arow + t * 8 + 4);
  float4 u0 = *(const float4*)(t2b + t * 8);
  float4 u1 = *(const float4*)(t2b + t * 8 + 4);
  float deg = a0.x + a0.y + a0.z + a0.w + a1.x + a1.y + a1.z + a1.w;
  float dot = a0.x * u0.x + a0.y * u0.y + a0.z * u0.z + a0.w * u0.w +
              a1.x * u1.x + a1.y * u1.y + a1.z * u1.z + a1.w * u1.w;
  unsigned mb = (a0.x > 0.f ? 1u : 0u) | (a0.y > 0.f ? 2u : 0u) |
                (a0.z > 0.f ? 4u : 0u) | (a0.w > 0.f ? 8u : 0u) |
                (a1.x > 0.f ? 16u : 0u) | (a1.y > 0.f ? 32u : 0u) |
                (a1.z > 0.f ? 64u : 0u) | (a1.w > 0.f ? 128u : 0u);
  mask[(size_t)row * 256 + t] = (unsigned char)mb;

  #pragma unroll
  for (int off = 32; off > 0; off >>= 1) {
    deg += __shfl_down(deg, off);
    dot += __shfl_down(dot, off);
  }
  __shared__ float rd[4], rt[4], rm[4], rz[4];
  if (lane == 0) { rd[wid] = deg; rt[wid] = dot; }
  __syncthreads();
  deg = rd[0] + rd[1] + rd[2] + rd[3];
  dot = rt[0] + rt[1] + rt[2] + rt[3];
  float degc = deg > 0.f ? deg : 1.f;
  float s2p = (dot / degc) * LOG2E;

  float4 p0 = *(const float4*)(t1b + t * 8);
  float4 p1 = *(const float4*)(t1b + t * 8 + 4);
  float al[8];
  al[0] = (mb & 1)   ? alpha_of(p0.x + s2p) : NEG_BIG;
  al[1] = (mb & 2)   ? alpha_of(p0.y + s2p) : NEG_BIG;
  al[2] = (mb & 4)   ? alpha_of(p0.z + s2p) : NEG_BIG;
  al[3] = (mb & 8)   ? alpha_of(p0.w + s2p) : NEG_BIG;
  al[4] = (mb & 16)  ? alpha_of(p1.x + s2p) : NEG_BIG;
  al[5] = (mb & 32)  ? alpha_of(p1.y + s2p) : NEG_BIG;
  al[6] = (mb & 64)  ? alpha_of(p1.z + s2p) : NEG_BIG;
  al[7] = (mb & 128) ? alpha_of(p1.w + s2p) : NEG_BIG;
  float m = NEG_BIG;
  #pragma unroll
  for (int j = 0; j < 8; ++j) m = fmaxf(m, al[j]);
  #pragma unroll
  for (int off = 32; off > 0; off >>= 1) m = fmaxf(m, __shfl_down(m, off));
  if (lane == 0) rm[wid] = m;
  __syncthreads();
  m = fmaxf(fmaxf(rm[0], rm[1]), fmaxf(rm[2], rm[3]));

  float negmL = -m * LOG2E;
  float z = 0.f;
  #pragma unroll
  for (int j = 0; j < 8; ++j) z += __builtin_amdgcn_exp2f(fmaf(al[j], LOG2E, negmL));
  #pragma unroll
  for (int off = 32; off > 0; off >>= 1) z += __shfl_down(z, off);
  if (lane == 0) rz[wid] = z;
  __syncthreads();
  if (t == 0) {
    z = rz[0] + rz[1] + rz[2] + rz[3];
    ws[WS_S2 + row] = s2p;
    if (deg > 0.f) {
      ws[WS_CR + row] = negmL - log2f(z);
      ws[WS_WN + row] = 0.f;
    } else {
      ws[WS_CR + row] = 0.f;
      ws[WS_WN + row] = 1.0f / (float)N;
    }
  }
}

// ---------------- kernel 4: fused weights + 32x32x16 MFMA GEMM ----------------
// grid 256, 512 threads (8 waves). TR=32 rows/block, TF=256 (full F), BK=128.
// Wave w = f-tile [w*32, w*32+32). bf direct from global (L2). Aw frag-ordered
// in LDS, ping-pong, one barrier per K-iter.
__global__ __launch_bounds__(512, 2) void k_gemm(const f16* __restrict__ wordT,
                                                 const unsigned char* __restrict__ maskg,
                                                 const float* __restrict__ ws,
                                                 float* __restrict__ out) {
  __shared__ __align__(16) f16 Aw[2][8][512];   // [buf][chunk][lane*8] halfs, 16KB
  __shared__ __align__(16) float t1S[N];        // 8KB
  __shared__ __align__(16) unsigned maskS[32][64]; // 8KB
  __shared__ float sSC[96];

  const int t = threadIdx.x;
  const int row0 = blockIdx.x * 32;
  const int b = row0 >> 11;

  *(float4*)&t1S[t * 4] = *(const float4*)(ws + WS_T1 + b * N + t * 4);
  *(uint4*)&maskS[t >> 4][(t & 15) * 4] =
      *(const uint4*)(maskg + (size_t)(row0 + (t >> 4)) * 256 + (t & 15) * 16);
  if (t < 32) {
    sSC[t]      = ws[WS_S2 + row0 + t];
    sSC[32 + t] = ws[WS_CR + row0 + t];
    sSC[64 + t] = ws[WS_WN + row0 + t];
  }
  __syncthreads();

  // weight-gen persistent indices: thread t -> (chunk gc, lane-slot gl)
  const int gl = t & 63;
  const int gc = t >> 6;                 // 0..7
  const int grow = gl & 31;
  const int gkb = gc * 16 + (gl >> 5) * 8;   // klocal base, 0..127
  const float rs2 = sSC[grow], rcr = sSC[32 + grow], rwn = sSC[64 + grow];

  // mfma persistent indices
  const int lw = t & 63;
  const int wv = t >> 6;                 // wave id = f-tile
  const int fcol = wv * 32 + (lw & 31);
  const f16* bptr = wordT + ((size_t)(b * F + fcol)) * N + (lw >> 5) * 8;

  f32x16 acc = {0.f,0.f,0.f,0.f,0.f,0.f,0.f,0.f,0.f,0.f,0.f,0.f,0.f,0.f,0.f,0.f};

  #define GENW(IT, BUF)                                                        \
    {                                                                          \
      const int kg = (IT) * 128 + gkb;                                         \
      const unsigned mw = maskS[grow][kg >> 5] >> (kg & 31);                   \
      const float4 tv0 = *(const float4*)&t1S[kg];                             \
      const float4 tv1 = *(const float4*)&t1S[kg + 4];                         \
      const float tvv[8] = {tv0.x, tv0.y, tv0.z, tv0.w,                        \
                            tv1.x, tv1.y, tv1.z, tv1.w};                       \
      f16x8 h;                                                                 \
      _Pragma("unroll")                                                        \
      for (int j = 0; j < 8; ++j) {                                            \
        float p = tvv[j] + rs2;                                                \
        float al = __builtin_amdgcn_exp2f(fmaxf(p, 0.2f * p));                 \
        float wsel = __builtin_amdgcn_exp2f(fmaf(al, LOG2E, rcr));             \
        float w = ((mw >> j) & 1u) ? wsel : rwn;                               \
        h[j] = (f16)w;                                                         \
      }                                                                        \
      *(f16x8*)&Aw[BUF][gc][gl * 8] = h;                                       \
    }

  GENW(0, 0)
  __syncthreads();

  for (int it = 0; it < 16; ++it) {
    const int cur = it & 1;
    f16x8 bf[8];
    const f16* bp = bptr + it * 128;
    #pragma unroll
    for (int c = 0; c < 8; ++c) bf[c] = *(const f16x8*)(bp + c * 16);
    if (it < 15) GENW(it + 1, cur ^ 1)
    #pragma unroll
    for (int c = 0; c < 8; ++c) {
      const f16x8 af = *(const f16x8*)&Aw[cur][c][lw * 8];
      acc = __builtin_amdgcn_mfma_f32_32x32x16_f16(af, bf[c], acc, 0, 0, 0);
    }
    __syncthreads();
  }

  // epilogue: C layout (m74/m101): col = lane&31, row = (reg&3)+8*(reg>>2)+4*(lane>>5)
  #pragma unroll
  for (int reg = 0; reg < 16; ++reg) {
    int lr = (reg & 3) + 8 * (reg >> 2) + 4 * (lw >> 5);
    out[(size_t)(row0 + lr) * F + fcol] = acc[reg];
  }
}

extern "C" void kernel_launch(void* const* d_in, const int* in_sizes, int n_in,
                              void* d_out, int out_size, void* d_ws, size_t ws_size,
                              hipStream_t stream) {
  const float* word = (const float*)d_in[0];
  const float* adj  = (const float*)d_in[1];
  const float* W1   = (const float*)d_in[2];
  const float* W2   = (const float*)d_in[3];
  const float* w3   = (const float*)d_in[4];
  float* out = (float*)d_out;
  float* ws  = (float*)d_ws;
  f16* wordT = (f16*)((char*)d_ws + WT_OFF);
  unsigned char* mask = (unsigned char*)d_ws + MK_OFF;

  k_v<<<64, 256, 0, stream>>>(W1, W2, w3, ws);
  k_prep<<<dim3(N / 32, B), 256, 0, stream>>>(word, ws, wordT);
  k_stats<<<B * N, 256, 0, stream>>>(adj, ws, mask);
  k_gemm<<<(B * N) / 32, 512, 0, stream>>>(wordT, mask, ws, out);
}

// Round 4
// 132.481 us; speedup vs baseline: 2.5577x; 1.1210x over previous
//
#include <hip/hip_runtime.h>

#define B 4
#define N 2048      // N1 == N2
#define F 256
#define O 256
#define LOG2E 1.4426950408889634f
#define NEG_BIG -9000000000000000.0f

typedef _Float16 f16;
typedef f16 f16x8 __attribute__((ext_vector_type(8)));
typedef float f32x16 __attribute__((ext_vector_type(16)));

// ws float-index layout
#define WS_V1 0
#define WS_V2 256
#define WS_T1 512              // t1 * LOG2E  per (b,n2)
#define WS_T2 (512 + B*N)     // t2 (unscaled) per (b,n2)
#define WS_S2 (512 + 2*B*N)   // s2 * LOG2E  per (b,n1)
#define WS_CR (512 + 3*B*N)   // -m*LOG2E - log2(Z)
#define WS_WN (512 + 4*B*N)   // weight for adj==0 entries (0, or 1/N for deg==0)
// byte offsets in d_ws
#define WT_OFF (1u << 20)     // wordT swizzled: f16 [B][ft(8)][kc(128)][lane(64)][8] (4 MB)
#define MK_OFF (6u << 20)     // mask: u8 [B*N][N/8] (2 MB)

__device__ __forceinline__ float alpha_of(float pre2) {
  return __builtin_amdgcn_exp2f(fmaxf(pre2, 0.2f * pre2));
}

// ---------------- kernel 1: v1 = W1 @ w3a, v2 = W2 @ w3b ----------------
__global__ __launch_bounds__(256) void k_v(const float* __restrict__ W1,
                                           const float* __restrict__ W2,
                                           const float* __restrict__ w3,
                                           float* __restrict__ ws) {
  int tid = threadIdx.x;
  int lane = tid & 63;
  int f = blockIdx.x * 4 + (tid >> 6);
  float a = 0.f, b = 0.f;
  #pragma unroll
  for (int k = 0; k < 4; ++k) {
    int o = lane + 64 * k;
    a += W1[f * O + o] * w3[o];
    b += W2[f * O + o] * w3[O + o];
  }
  #pragma unroll
  for (int off = 32; off > 0; off >>= 1) {
    a += __shfl_down(a, off);
    b += __shfl_down(b, off);
  }
  if (lane == 0) {
    ws[WS_V1 + f] = a;
    ws[WS_V2 + f] = b;
  }
}

// ---------------- kernel 2: k_prep = t1/t2 dots + swizzled f16 transpose ----
// grid (N/32, B), 256 threads. Block: 32 k-rows -> t1,t2 + wordT frag tiles.
__global__ __launch_bounds__(256) void k_prep(const float* __restrict__ word,
                                              float* __restrict__ ws,
                                              f16* __restrict__ wordT) {
  __shared__ float v1s[F], v2s[F];
  __shared__ __align__(16) f16 tile[F][40];   // [f][r]
  int t = threadIdx.x;
  int k0 = blockIdx.x * 32;
  int b = blockIdx.y;

  if (t < 64)       ((float4*)v1s)[t]      = ((const float4*)(ws + WS_V1))[t];
  else if (t < 128) ((float4*)v2s)[t - 64] = ((const float4*)(ws + WS_V2))[t - 64];
  __syncthreads();

  int r = t >> 3;        // 0..31
  int cg = t & 7;
  const float* wrow = word + ((size_t)(b * N + k0 + r)) * F;
  float a = 0.f, bb = 0.f;
  #pragma unroll
  for (int i = 0; i < 8; ++i) {
    int c = i * 32 + cg * 4;
    float4 w = *(const float4*)(wrow + c);
    float4 x1 = *(const float4*)(v1s + c);
    float4 x2 = *(const float4*)(v2s + c);
    a  += w.x * x1.x + w.y * x1.y + w.z * x1.z + w.w * x1.w;
    bb += w.x * x2.x + w.y * x2.y + w.z * x2.z + w.w * x2.w;
    tile[c + 0][r] = (f16)w.x;
    tile[c + 1][r] = (f16)w.y;
    tile[c + 2][r] = (f16)w.z;
    tile[c + 3][r] = (f16)w.w;
  }
  #pragma unroll
  for (int off = 4; off > 0; off >>= 1) {
    a  += __shfl_down(a, off);
    bb += __shfl_down(bb, off);
  }
  if (cg == 0) {
    ws[WS_T1 + b * N + k0 + r] = a * LOG2E;
    ws[WS_T2 + b * N + k0 + r] = bb;
  }
  __syncthreads();

  // swizzled writes: [ft][kc][lane][8]; B-frag: f = ft*32+(l&31), k = kc*16+(l>>5)*8+j
  size_t base = (size_t)b * F * N;
  #pragma unroll
  for (int i = 0; i < 4; ++i) {
    int idx = t + 256 * i;
    int ft = idx >> 7, c = (idx >> 6) & 1, l = idx & 63;
    int f = ft * 32 + (l & 31);
    int rr = c * 16 + ((l >> 5) * 8);
    f16x8 h = *(const f16x8*)&tile[f][rr];
    *(f16x8*)(wordT + base + ((size_t)((ft * 128 + (k0 >> 4) + c) * 64 + l)) * 8) = h;
  }
}

// ---------------- kernel 3: per-row stats + packed bitmask ----------------
__global__ __launch_bounds__(256) void k_stats(const float* __restrict__ adj,
                                               float* __restrict__ ws,
                                               unsigned char* __restrict__ mask) {
  int row = blockIdx.x;
  int b = row >> 11;
  int t = threadIdx.x;
  int wid = t >> 6, lane = t & 63;
  const float* arow = adj + (size_t)row * N;
  const float* t1b = ws + WS_T1 + b * N;
  const float* t2b = ws + WS_T2 + b * N;

  float4 a0 = *(const float4*)(arow + t * 8);
  float4 a1 = *(const float4*)(arow + t * 8 + 4);
  float4 u0 = *(const float4*)(t2b + t * 8);
  float4 u1 = *(const float4*)(t2b + t * 8 + 4);
  float deg = a0.x + a0.y + a0.z + a0.w + a1.x + a1.y + a1.z + a1.w;
  float dot = a0.x * u0.x + a0.y * u0.y + a0.z * u0.z + a0.w * u0.w +
              a1.x * u1.x + a1.y * u1.y + a1.z * u1.z + a1.w * u1.w;
  unsigned mb = (a0.x > 0.f ? 1u : 0u) | (a0.y > 0.f ? 2u : 0u) |
                (a0.z > 0.f ? 4u : 0u) | (a0.w > 0.f ? 8u : 0u) |
                (a1.x > 0.f ? 16u : 0u) | (a1.y > 0.f ? 32u : 0u) |
                (a1.z > 0.f ? 64u : 0u) | (a1.w > 0.f ? 128u : 0u);
  mask[(size_t)row * 256 + t] = (unsigned char)mb;

  #pragma unroll
  for (int off = 32; off > 0; off >>= 1) {
    deg += __shfl_down(deg, off);
    dot += __shfl_down(dot, off);
  }
  __shared__ float rd[4], rt[4], rm[4], rz[4];
  if (lane == 0) { rd[wid] = deg; rt[wid] = dot; }
  __syncthreads();
  deg = rd[0] + rd[1] + rd[2] + rd[3];
  dot = rt[0] + rt[1] + rt[2] + rt[3];
  float degc = deg > 0.f ? deg : 1.f;
  float s2p = (dot / degc) * LOG2E;

  float4 p0 = *(const float4*)(t1b + t * 8);
  float4 p1 = *(const float4*)(t1b + t * 8 + 4);
  float al[8];
  al[0] = (mb & 1)   ? alpha_of(p0.x + s2p) : NEG_BIG;
  al[1] = (mb & 2)   ? alpha_of(p0.y + s2p) : NEG_BIG;
  al[2] = (mb & 4)   ? alpha_of(p0.z + s2p) : NEG_BIG;
  al[3] = (mb & 8)   ? alpha_of(p0.w + s2p) : NEG_BIG;
  al[4] = (mb & 16)  ? alpha_of(p1.x + s2p) : NEG_BIG;
  al[5] = (mb & 32)  ? alpha_of(p1.y + s2p) : NEG_BIG;
  al[6] = (mb & 64)  ? alpha_of(p1.z + s2p) : NEG_BIG;
  al[7] = (mb & 128) ? alpha_of(p1.w + s2p) : NEG_BIG;
  float m = NEG_BIG;
  #pragma unroll
  for (int j = 0; j < 8; ++j) m = fmaxf(m, al[j]);
  #pragma unroll
  for (int off = 32; off > 0; off >>= 1) m = fmaxf(m, __shfl_down(m, off));
  if (lane == 0) rm[wid] = m;
  __syncthreads();
  m = fmaxf(fmaxf(rm[0], rm[1]), fmaxf(rm[2], rm[3]));

  float negmL = -m * LOG2E;
  float z = 0.f;
  #pragma unroll
  for (int j = 0; j < 8; ++j) z += __builtin_amdgcn_exp2f(fmaf(al[j], LOG2E, negmL));
  #pragma unroll
  for (int off = 32; off > 0; off >>= 1) z += __shfl_down(z, off);
  if (lane == 0) rz[wid] = z;
  __syncthreads();
  if (t == 0) {
    z = rz[0] + rz[1] + rz[2] + rz[3];
    ws[WS_S2 + row] = s2p;
    if (deg > 0.f) {
      ws[WS_CR + row] = negmL - log2f(z);
      ws[WS_WN + row] = 0.f;
    } else {
      ws[WS_CR + row] = 0.f;
      ws[WS_WN + row] = 1.0f / (float)N;
    }
  }
}

// ---------------- kernel 4: fused weights + 32x32x16 MFMA GEMM ----------------
// grid 256 (rb*2+fh), 512 threads (8 waves). TR=64 rows, TF=128 cols, BK=128.
// Wave wv: rh = wv>>2 (row half), ftl = wv&3; f-tile = fh*4+ftl.
// B: direct global, frag-ordered (coalesced 1KB/instr). A: LDS ping-pong.
__global__ __launch_bounds__(512, 1) void k_gemm(const f16* __restrict__ wordT,
                                                 const unsigned char* __restrict__ maskg,
                                                 const float* __restrict__ ws,
                                                 float* __restrict__ out) {
  __shared__ __align__(16) f16 Aw[2][2][8][512];  // [buf][rh][chunk][lane*8]  32KB
  __shared__ __align__(16) float t1S[N];          // 8KB
  __shared__ float sSC[192];

  const int t = threadIdx.x;
  const int rb = blockIdx.x >> 1, fh = blockIdx.x & 1;
  const int row0 = rb * 64;
  const int b = row0 >> 11;

  *(float4*)&t1S[t * 4] = *(const float4*)(ws + WS_T1 + b * N + t * 4);
  if (t < 64) {
    sSC[t]       = ws[WS_S2 + row0 + t];
    sSC[64 + t]  = ws[WS_CR + row0 + t];
    sSC[128 + t] = ws[WS_WN + row0 + t];
  }
  __syncthreads();

  // weight-gen persistent indices
  const int gl = t & 63;
  const int gc = (t >> 6) & 3;          // chunk-pair id 0..3 -> chunks {2gc, 2gc+1}
  const int rh_g = t >> 8;              // 0..1
  const int koff = (gl >> 5) * 8;
  const int rowL = rh_g * 32 + (gl & 31);
  const float rs2 = sSC[rowL], rcr = sSC[64 + rowL], rwn = sSC[128 + rowL];
  const unsigned* mrow = (const unsigned*)(maskg + (size_t)(row0 + rowL) * 256);

  // mfma persistent indices
  const int lw = t & 63;
  const int wv = t >> 6;
  const int rh = wv >> 2;
  const int ftile = fh * 4 + (wv & 3);
  const int fcol = ftile * 32 + (lw & 31);
  const f16* wtb = wordT + (size_t)b * F * N;

  f32x16 acc = {0.f,0.f,0.f,0.f,0.f,0.f,0.f,0.f,0.f,0.f,0.f,0.f,0.f,0.f,0.f,0.f};

  #define GENW(IT, BUF, MW)                                                    \
    {                                                                          \
      const int kb = (IT) * 128 + gc * 32 + koff;                              \
      const float4 ta0 = *(const float4*)&t1S[kb];                             \
      const float4 ta1 = *(const float4*)&t1S[kb + 4];                         \
      const float4 tb0 = *(const float4*)&t1S[kb + 16];                        \
      const float4 tb1 = *(const float4*)&t1S[kb + 20];                        \
      const float ta[8] = {ta0.x, ta0.y, ta0.z, ta0.w, ta1.x, ta1.y, ta1.z, ta1.w}; \
      const float tb[8] = {tb0.x, tb0.y, tb0.z, tb0.w, tb1.x, tb1.y, tb1.z, tb1.w}; \
      const unsigned m0 = (MW) >> koff;                                        \
      const unsigned m1 = (MW) >> (16 + koff);                                 \
      f16x8 h0, h1;                                                            \
      _Pragma("unroll")                                                        \
      for (int j = 0; j < 8; ++j) {                                            \
        float p0 = ta[j] + rs2;                                                \
        float a0v = __builtin_amdgcn_exp2f(fmaxf(p0, 0.2f * p0));              \
        float w0 = ((m0 >> j) & 1u) ? __builtin_amdgcn_exp2f(fmaf(a0v, LOG2E, rcr)) : rwn; \
        h0[j] = (f16)w0;                                                       \
        float p1 = tb[j] + rs2;                                                \
        float a1v = __builtin_amdgcn_exp2f(fmaxf(p1, 0.2f * p1));              \
        float w1 = ((m1 >> j) & 1u) ? __builtin_amdgcn_exp2f(fmaf(a1v, LOG2E, rcr)) : rwn; \
        h1[j] = (f16)w1;                                                       \
      }                                                                        \
      *(f16x8*)&Aw[BUF][rh_g][gc * 2][gl * 8]     = h0;                        \
      *(f16x8*)&Aw[BUF][rh_g][gc * 2 + 1][gl * 8] = h1;                        \
    }

  {
    unsigned mw0 = mrow[gc];
    GENW(0, 0, mw0)
  }
  __syncthreads();

  for (int it = 0; it < 16; ++it) {
    const int cur = it & 1;
    // B loads: frag-ordered, lane-contiguous 16B -> coalesced
    const f16* bp = wtb + ((size_t)(ftile * 128 + it * 8) * 64 + lw) * 8;
    f16x8 bf[8];
    #pragma unroll
    for (int c = 0; c < 8; ++c) bf[c] = *(const f16x8*)(bp + (size_t)c * 512);

    if (it < 15) {
      unsigned mwn = mrow[(it + 1) * 4 + gc];
      GENW(it + 1, cur ^ 1, mwn)
    }

    #pragma unroll
    for (int c = 0; c < 8; ++c) {
      const f16x8 af = *(const f16x8*)&Aw[cur][rh][c][lw * 8];
      acc = __builtin_amdgcn_mfma_f32_32x32x16_f16(af, bf[c], acc, 0, 0, 0);
    }
    __syncthreads();
  }

  // epilogue: C layout: col = lane&31, row = (reg&3)+8*(reg>>2)+4*(lane>>5)
  #pragma unroll
  for (int reg = 0; reg < 16; ++reg) {
    int lr = rh * 32 + (reg & 3) + 8 * (reg >> 2) + 4 * (lw >> 5);
    out[(size_t)(row0 + lr) * F + fcol] = acc[reg];
  }
}

extern "C" void kernel_launch(void* const* d_in, const int* in_sizes, int n_in,
                              void* d_out, int out_size, void* d_ws, size_t ws_size,
                              hipStream_t stream) {
  const float* word = (const float*)d_in[0];
  const float* adj  = (const float*)d_in[1];
  const float* W1   = (const float*)d_in[2];
  const float* W2   = (const float*)d_in[3];
  const float* w3   = (const float*)d_in[4];
  float* out = (float*)d_out;
  float* ws  = (float*)d_ws;
  f16* wordT = (f16*)((char*)d_ws + WT_OFF);
  unsigned char* mask = (unsigned char*)d_ws + MK_OFF;

  k_v<<<64, 256, 0, stream>>>(W1, W2, w3, ws);
  k_prep<<<dim3(N / 32, B), 256, 0, stream>>>(word, ws, wordT);
  k_stats<<<B * N, 256, 0, stream>>>(adj, ws, mask);
  k_gemm<<<(B * N) / 64 * 2, 512, 0, stream>>>(wordT, mask, ws, out);
}

// Round 5
// 131.938 us; speedup vs baseline: 2.5682x; 1.0041x over previous
//
#include <hip/hip_runtime.h>

#define B 4
#define N 2048      // N1 == N2
#define F 256
#define O 256
#define LOG2E 1.4426950408889634f
#define NEG_BIG -9000000000000000.0f

typedef _Float16 f16;
typedef f16 f16x8 __attribute__((ext_vector_type(8)));
typedef float f32x16 __attribute__((ext_vector_type(16)));

// ws float-index layout
#define WS_V1 0
#define WS_V2 256
#define WS_T1 512              // t1 * LOG2E  per (b,n2)
#define WS_T2 (512 + B*N)     // t2 (unscaled) per (b,n2)
#define WS_S2 (512 + 2*B*N)   // s2 * LOG2E  per (b,n1)
#define WS_CR (512 + 3*B*N)   // -m*LOG2E - log2(Z)
#define WS_WN (512 + 4*B*N)   // weight for adj==0 entries (0, or 1/N for deg==0)
// byte offsets in d_ws
#define WT_OFF (1u << 20)     // wordT swizzled: f16 [B][ft(8)][kc(128)][lane(64)][8] (4 MB)
#define MK_OFF (6u << 20)     // mask: u8 [B*N][N/8] (2 MB)

__device__ __forceinline__ float alpha_of(float pre2) {
  return __builtin_amdgcn_exp2f(fmaxf(pre2, 0.2f * pre2));
}

// ---------------- kernel 1: v1 = W1 @ w3a, v2 = W2 @ w3b ----------------
__global__ __launch_bounds__(256) void k_v(const float* __restrict__ W1,
                                           const float* __restrict__ W2,
                                           const float* __restrict__ w3,
                                           float* __restrict__ ws) {
  int tid = threadIdx.x;
  int lane = tid & 63;
  int f = blockIdx.x * 4 + (tid >> 6);
  float a = 0.f, b = 0.f;
  #pragma unroll
  for (int k = 0; k < 4; ++k) {
    int o = lane + 64 * k;
    a += W1[f * O + o] * w3[o];
    b += W2[f * O + o] * w3[O + o];
  }
  #pragma unroll
  for (int off = 32; off > 0; off >>= 1) {
    a += __shfl_down(a, off);
    b += __shfl_down(b, off);
  }
  if (lane == 0) {
    ws[WS_V1 + f] = a;
    ws[WS_V2 + f] = b;
  }
}

// ---------------- kernel 2: k_prep = t1/t2 dots + swizzled f16 transpose ----
__global__ __launch_bounds__(256) void k_prep(const float* __restrict__ word,
                                              float* __restrict__ ws,
                                              f16* __restrict__ wordT) {
  __shared__ float v1s[F], v2s[F];
  __shared__ __align__(16) f16 tile[F][40];   // [f][r]
  int t = threadIdx.x;
  int k0 = blockIdx.x * 32;
  int b = blockIdx.y;

  if (t < 64)       ((float4*)v1s)[t]      = ((const float4*)(ws + WS_V1))[t];
  else if (t < 128) ((float4*)v2s)[t - 64] = ((const float4*)(ws + WS_V2))[t - 64];
  __syncthreads();

  int r = t >> 3;        // 0..31
  int cg = t & 7;
  const float* wrow = word + ((size_t)(b * N + k0 + r)) * F;
  float a = 0.f, bb = 0.f;
  #pragma unroll
  for (int i = 0; i < 8; ++i) {
    int c = i * 32 + cg * 4;
    float4 w = *(const float4*)(wrow + c);
    float4 x1 = *(const float4*)(v1s + c);
    float4 x2 = *(const float4*)(v2s + c);
    a  += w.x * x1.x + w.y * x1.y + w.z * x1.z + w.w * x1.w;
    bb += w.x * x2.x + w.y * x2.y + w.z * x2.z + w.w * x2.w;
    tile[c + 0][r] = (f16)w.x;
    tile[c + 1][r] = (f16)w.y;
    tile[c + 2][r] = (f16)w.z;
    tile[c + 3][r] = (f16)w.w;
  }
  #pragma unroll
  for (int off = 4; off > 0; off >>= 1) {
    a  += __shfl_down(a, off);
    bb += __shfl_down(bb, off);
  }
  if (cg == 0) {
    ws[WS_T1 + b * N + k0 + r] = a * LOG2E;
    ws[WS_T2 + b * N + k0 + r] = bb;
  }
  __syncthreads();

  // swizzled writes: [ft][kc][lane][8]; B-frag: f = ft*32+(l&31), k = kc*16+(l>>5)*8+j
  size_t base = (size_t)b * F * N;
  #pragma unroll
  for (int i = 0; i < 4; ++i) {
    int idx = t + 256 * i;
    int ft = idx >> 7, c = (idx >> 6) & 1, l = idx & 63;
    int f = ft * 32 + (l & 31);
    int rr = c * 16 + ((l >> 5) * 8);
    f16x8 h = *(const f16x8*)&tile[f][rr];
    *(f16x8*)(wordT + base + ((size_t)((ft * 128 + (k0 >> 4) + c) * 64 + l)) * 8) = h;
  }
}

// ---------------- kernel 3: per-row stats + packed bitmask ----------------
__global__ __launch_bounds__(256) void k_stats(const float* __restrict__ adj,
                                               float* __restrict__ ws,
                                               unsigned char* __restrict__ mask) {
  int row = blockIdx.x;
  int b = row >> 11;
  int t = threadIdx.x;
  int wid = t >> 6, lane = t & 63;
  const float* arow = adj + (size_t)row * N;
  const float* t1b = ws + WS_T1 + b * N;
  const float* t2b = ws + WS_T2 + b * N;

  float4 a0 = *(const float4*)(arow + t * 8);
  float4 a1 = *(const float4*)(arow + t * 8 + 4);
  float4 u0 = *(const float4*)(t2b + t * 8);
  float4 u1 = *(const float4*)(t2b + t * 8 + 4);
  float deg = a0.x + a0.y + a0.z + a0.w + a1.x + a1.y + a1.z + a1.w;
  float dot = a0.x * u0.x + a0.y * u0.y + a0.z * u0.z + a0.w * u0.w +
              a1.x * u1.x + a1.y * u1.y + a1.z * u1.z + a1.w * u1.w;
  unsigned mb = (a0.x > 0.f ? 1u : 0u) | (a0.y > 0.f ? 2u : 0u) |
                (a0.z > 0.f ? 4u : 0u) | (a0.w > 0.f ? 8u : 0u) |
                (a1.x > 0.f ? 16u : 0u) | (a1.y > 0.f ? 32u : 0u) |
                (a1.z > 0.f ? 64u : 0u) | (a1.w > 0.f ? 128u : 0u);
  mask[(size_t)row * 256 + t] = (unsigned char)mb;

  #pragma unroll
  for (int off = 32; off > 0; off >>= 1) {
    deg += __shfl_down(deg, off);
    dot += __shfl_down(dot, off);
  }
  __shared__ float rd[4], rt[4], rm[4], rz[4];
  if (lane == 0) { rd[wid] = deg; rt[wid] = dot; }
  __syncthreads();
  deg = rd[0] + rd[1] + rd[2] + rd[3];
  dot = rt[0] + rt[1] + rt[2] + rt[3];
  float degc = deg > 0.f ? deg : 1.f;
  float s2p = (dot / degc) * LOG2E;

  float4 p0 = *(const float4*)(t1b + t * 8);
  float4 p1 = *(const float4*)(t1b + t * 8 + 4);
  float al[8];
  al[0] = (mb & 1)   ? alpha_of(p0.x + s2p) : NEG_BIG;
  al[1] = (mb & 2)   ? alpha_of(p0.y + s2p) : NEG_BIG;
  al[2] = (mb & 4)   ? alpha_of(p0.z + s2p) : NEG_BIG;
  al[3] = (mb & 8)   ? alpha_of(p0.w + s2p) : NEG_BIG;
  al[4] = (mb & 16)  ? alpha_of(p1.x + s2p) : NEG_BIG;
  al[5] = (mb & 32)  ? alpha_of(p1.y + s2p) : NEG_BIG;
  al[6] = (mb & 64)  ? alpha_of(p1.z + s2p) : NEG_BIG;
  al[7] = (mb & 128) ? alpha_of(p1.w + s2p) : NEG_BIG;
  float m = NEG_BIG;
  #pragma unroll
  for (int j = 0; j < 8; ++j) m = fmaxf(m, al[j]);
  #pragma unroll
  for (int off = 32; off > 0; off >>= 1) m = fmaxf(m, __shfl_down(m, off));
  if (lane == 0) rm[wid] = m;
  __syncthreads();
  m = fmaxf(fmaxf(rm[0], rm[1]), fmaxf(rm[2], rm[3]));

  float negmL = -m * LOG2E;
  float z = 0.f;
  #pragma unroll
  for (int j = 0; j < 8; ++j) z += __builtin_amdgcn_exp2f(fmaf(al[j], LOG2E, negmL));
  #pragma unroll
  for (int off = 32; off > 0; off >>= 1) z += __shfl_down(z, off);
  if (lane == 0) rz[wid] = z;
  __syncthreads();
  if (t == 0) {
    z = rz[0] + rz[1] + rz[2] + rz[3];
    ws[WS_S2 + row] = s2p;
    if (deg > 0.f) {
      ws[WS_CR + row] = negmL - log2f(z);
      ws[WS_WN + row] = 0.f;
    } else {
      ws[WS_CR + row] = 0.f;
      ws[WS_WN + row] = 1.0f / (float)N;
    }
  }
}

// ---------------- kernel 4: fused weights + 32x32x16 MFMA GEMM ----------------
// grid 512 (rb*2+fh), 256 threads (4 waves) -> 2 blocks/CU co-resident.
// TR=32 rows, TF=128 cols, BK=128. Wave wv = f-tile fh*4+wv.
// B: direct global, frag-ordered (coalesced), register-prefetched one iter ahead.
// A (weights): LDS ping-pong, one barrier/iter.
__global__ __launch_bounds__(256, 2) void k_gemm(const f16* __restrict__ wordT,
                                                 const unsigned char* __restrict__ maskg,
                                                 const float* __restrict__ ws,
                                                 float* __restrict__ out) {
  __shared__ __align__(16) f16 Aw[2][8][512];   // [buf][chunk][lane*8]  16KB
  __shared__ __align__(16) float t1S[N];        // 8KB
  __shared__ float sSC[96];

  const int t = threadIdx.x;
  const int rb = blockIdx.x >> 1, fh = blockIdx.x & 1;
  const int row0 = rb * 32;
  const int b = row0 >> 11;

  *(float4*)&t1S[t * 8]     = *(const float4*)(ws + WS_T1 + b * N + t * 8);
  *(float4*)&t1S[t * 8 + 4] = *(const float4*)(ws + WS_T1 + b * N + t * 8 + 4);
  if (t < 32) {
    sSC[t]      = ws[WS_S2 + row0 + t];
    sSC[32 + t] = ws[WS_CR + row0 + t];
    sSC[64 + t] = ws[WS_WN + row0 + t];
  }
  __syncthreads();

  // weight-gen persistent indices: thread t -> chunk-pair gp, lane-slot gl
  const int gl = t & 63;
  const int gp = t >> 6;                 // 0..3 -> chunks {2gp, 2gp+1}
  const int koff = (gl >> 5) * 8;
  const int rowL = gl & 31;
  const float rs2 = sSC[rowL], rcr = sSC[32 + rowL], rwn = sSC[64 + rowL];
  const unsigned* mrow = (const unsigned*)(maskg + (size_t)(row0 + rowL) * 256);

  // mfma persistent indices
  const int lw = t & 63;
  const int wv = t >> 6;
  const int ftile = fh * 4 + wv;
  const int fcol = ftile * 32 + (lw & 31);
  const f16* wtb = wordT + (size_t)b * F * N;

  f32x16 acc = {0.f,0.f,0.f,0.f,0.f,0.f,0.f,0.f,0.f,0.f,0.f,0.f,0.f,0.f,0.f,0.f};

  #define GENW(IT, BUF, MW)                                                    \
    {                                                                          \
      const int kb = (IT) * 128 + gp * 32 + koff;                              \
      const float4 ta0 = *(const float4*)&t1S[kb];                             \
      const float4 ta1 = *(const float4*)&t1S[kb + 4];                         \
      const float4 tb0 = *(const float4*)&t1S[kb + 16];                        \
      const float4 tb1 = *(const float4*)&t1S[kb + 20];                        \
      const float ta[8] = {ta0.x, ta0.y, ta0.z, ta0.w, ta1.x, ta1.y, ta1.z, ta1.w}; \
      const float tb[8] = {tb0.x, tb0.y, tb0.z, tb0.w, tb1.x, tb1.y, tb1.z, tb1.w}; \
      const unsigned m0 = (MW) >> koff;                                        \
      const unsigned m1 = (MW) >> (16 + koff);                                 \
      f16x8 h0, h1;                                                            \
      _Pragma("unroll")                                                        \
      for (int j = 0; j < 8; ++j) {                                            \
        float p0 = ta[j] + rs2;                                                \
        float a0v = __builtin_amdgcn_exp2f(fmaxf(p0, 0.2f * p0));              \
        float w0 = ((m0 >> j) & 1u) ? __builtin_amdgcn_exp2f(fmaf(a0v, LOG2E, rcr)) : rwn; \
        h0[j] = (f16)w0;                                                       \
        float p1 = tb[j] + rs2;                                                \
        float a1v = __builtin_amdgcn_exp2f(fmaxf(p1, 0.2f * p1));              \
        float w1 = ((m1 >> j) & 1u) ? __builtin_amdgcn_exp2f(fmaf(a1v, LOG2E, rcr)) : rwn; \
        h1[j] = (f16)w1;                                                       \
      }                                                                        \
      *(f16x8*)&Aw[BUF][gp * 2][gl * 8]     = h0;                              \
      *(f16x8*)&Aw[BUF][gp * 2 + 1][gl * 8] = h1;                              \
    }

  // prologue: B tile 0 + A tile 0
  f16x8 bf[8];
  {
    const f16* bp = wtb + ((size_t)(ftile * 128) * 64 + lw) * 8;
    #pragma unroll
    for (int c = 0; c < 8; ++c) bf[c] = *(const f16x8*)(bp + (size_t)c * 512);
  }
  {
    unsigned mw0 = mrow[gp];
    GENW(0, 0, mw0)
  }
  __syncthreads();

  #pragma unroll 2
  for (int it = 0; it < 16; ++it) {
    const int cur = it & 1;
    f16x8 bfn[8];
    if (it < 15) {
      // prefetch next B tile (in flight across the MFMAs + barrier)
      const f16* bp = wtb + ((size_t)(ftile * 128 + (it + 1) * 8) * 64 + lw) * 8;
      #pragma unroll
      for (int c = 0; c < 8; ++c) bfn[c] = *(const f16x8*)(bp + (size_t)c * 512);
      unsigned mwn = mrow[(it + 1) * 4 + gp];
      GENW(it + 1, cur ^ 1, mwn)
    }

    #pragma unroll
    for (int c = 0; c < 8; ++c) {
      const f16x8 af = *(const f16x8*)&Aw[cur][c][lw * 8];
      acc = __builtin_amdgcn_mfma_f32_32x32x16_f16(af, bf[c], acc, 0, 0, 0);
    }
    __syncthreads();

    if (it < 15) {
      #pragma unroll
      for (int c = 0; c < 8; ++c) bf[c] = bfn[c];
    }
  }

  // epilogue: C layout: col = lane&31, row = (reg&3)+8*(reg>>2)+4*(lane>>5)
  #pragma unroll
  for (int reg = 0; reg < 16; ++reg) {
    int lr = (reg & 3) + 8 * (reg >> 2) + 4 * (lw >> 5);
    out[(size_t)(row0 + lr) * F + fcol] = acc[reg];
  }
}

extern "C" void kernel_launch(void* const* d_in, const int* in_sizes, int n_in,
                              void* d_out, int out_size, void* d_ws, size_t ws_size,
                              hipStream_t stream) {
  const float* word = (const float*)d_in[0];
  const float* adj  = (const float*)d_in[1];
  const float* W1   = (const float*)d_in[2];
  const float* W2   = (const float*)d_in[3];
  const float* w3   = (const float*)d_in[4];
  float* out = (float*)d_out;
  float* ws  = (float*)d_ws;
  f16* wordT = (f16*)((char*)d_ws + WT_OFF);
  unsigned char* mask = (unsigned char*)d_ws + MK_OFF;

  k_v<<<64, 256, 0, stream>>>(W1, W2, w3, ws);
  k_prep<<<dim3(N / 32, B), 256, 0, stream>>>(word, ws, wordT);
  k_stats<<<B * N, 256, 0, stream>>>(adj, ws, mask);
  k_gemm<<<(B * N) / 32 * 2, 256, 0, stream>>>(wordT, mask, ws, out);
}